// Round 4
// baseline (173.431 us; speedup 1.0000x reference)
//
#include <hip/hip_runtime.h>
#include <cstdint>
#include <cstddef>

// Problem constants (fixed by setup_inputs)
#define BB 4
#define NN 8192
#define MM 4096
#define CC 64
#define SS 32
#define CH 67      // 3 (xyz) + 64 (features)

// radius^2 exactly as Python computes it: double 0.12*0.12 rounded once to f32.
__device__ __constant__ float kRR = (float)(0.12 * 0.12);

// ---- k1: transpose xyz (B,N,3) -> permuted SoA (B,3,N) in workspace --------
// Point n = t*256 + J*64 + l is stored at slot t*256 + 4*l + J, so that a
// float4 load by lane l at chunk t yields points {t*256 + J*64 + l, J=0..3}:
// sub-ballot J then covers a CONTIGUOUS 64-index range (preserves index order).
__global__ __launch_bounds__(256) void transpose_xyz(const float* __restrict__ xyz,
                                                     float* __restrict__ xt) {
    const int p = blockIdx.x * blockDim.x + threadIdx.x;  // 0 .. B*N-1
    if (p >= BB * NN) return;
    const int b = p / NN, n = p % NN;
    const int t = n >> 8;          // 256-point chunk
    const int r = n & 255;
    const int J = r >> 6;          // 64-group within chunk
    const int l = r & 63;          // lane
    const int slot = (t << 8) + (l << 2) + J;
    const float x = xyz[(size_t)p * 3 + 0];
    const float y = xyz[(size_t)p * 3 + 1];
    const float z = xyz[(size_t)p * 3 + 2];
    float* o = xt + (size_t)b * 3 * NN;
    o[0 * NN + slot] = x;
    o[1 * NN + slot] = y;
    o[2 * NN + slot] = z;
}

// ---- k2: fused ball-query + group ------------------------------------------
// One wave per query. Chunk = 256 points; 4 ordered sub-ballots per chunk,
// sub-ballot J = true indices TB + J*64 + lane (contiguous, index-ordered).

#define SUB_ROUND(J, HJ)                                                       \
    {                                                                          \
        const int pc = (int)__popcll(msk##J);                                  \
        if (pc) {                                                              \
            const int rank = cnt + (int)__popcll(msk##J & below);              \
            const int addr = ((HJ) && rank < 64) ? (rank << 2) : (63 << 2);    \
            const int recv = __builtin_amdgcn_ds_permute(                      \
                addr, TB + (J << 6) + lane);                                   \
            if (lane >= cnt && lane < cnt + pc && lane < SS) my_nb = recv;     \
            cnt += pc;                                                         \
        }                                                                      \
    }

#define PROCESS_CHUNK(xx, yy, zz, TB_EXPR)                                     \
    {                                                                          \
        const int TB = (TB_EXPR);                                              \
        float dx, dy, dz, d2;                                                  \
        dx = __fsub_rn((xx).x, cx); dy = __fsub_rn((yy).x, cy);                \
        dz = __fsub_rn((zz).x, cz);                                            \
        d2 = __fadd_rn(__fadd_rn(__fmul_rn(dx, dx), __fmul_rn(dy, dy)),        \
                       __fmul_rn(dz, dz));                                     \
        const bool h0 = d2 < rr;                                               \
        dx = __fsub_rn((xx).y, cx); dy = __fsub_rn((yy).y, cy);                \
        dz = __fsub_rn((zz).y, cz);                                            \
        d2 = __fadd_rn(__fadd_rn(__fmul_rn(dx, dx), __fmul_rn(dy, dy)),        \
                       __fmul_rn(dz, dz));                                     \
        const bool h1 = d2 < rr;                                               \
        dx = __fsub_rn((xx).z, cx); dy = __fsub_rn((yy).z, cy);                \
        dz = __fsub_rn((zz).z, cz);                                            \
        d2 = __fadd_rn(__fadd_rn(__fmul_rn(dx, dx), __fmul_rn(dy, dy)),        \
                       __fmul_rn(dz, dz));                                     \
        const bool h2 = d2 < rr;                                               \
        dx = __fsub_rn((xx).w, cx); dy = __fsub_rn((yy).w, cy);                \
        dz = __fsub_rn((zz).w, cz);                                            \
        d2 = __fadd_rn(__fadd_rn(__fmul_rn(dx, dx), __fmul_rn(dy, dy)),        \
                       __fmul_rn(dz, dz));                                     \
        const bool h3 = d2 < rr;                                               \
        const unsigned long long msk0 = __ballot(h0);                          \
        const unsigned long long msk1 = __ballot(h1);                          \
        const unsigned long long msk2 = __ballot(h2);                          \
        const unsigned long long msk3 = __ballot(h3);                          \
        if (msk0 | msk1 | msk2 | msk3) {                                       \
            SUB_ROUND(0, h0)                                                   \
            SUB_ROUND(1, h1)                                                   \
            SUB_ROUND(2, h2)                                                   \
            SUB_ROUND(3, h3)                                                   \
        }                                                                      \
    }

__global__ __launch_bounds__(256) void qg_soa_kernel(
    const float* __restrict__ xt,       // (B,3,N) permuted SoA in ws
    const float* __restrict__ xyz,      // (B,N,3) original AoS (for gather)
    const float* __restrict__ new_xyz,  // (B,M,3)
    const float* __restrict__ feat,     // (B,C,N)
    float* __restrict__ out)            // (B,67,M,32)
{
    const int wave = (int)((blockIdx.x * blockDim.x + threadIdx.x) >> 6);
    const int lane = (int)(threadIdx.x & 63);
    const int b = wave / MM;
    const int m = wave % MM;

    const float* __restrict__ xs = xt + (size_t)b * 3 * NN;
    const float4* __restrict__ X4 = (const float4*)(xs);
    const float4* __restrict__ Y4 = (const float4*)(xs + NN);
    const float4* __restrict__ Z4 = (const float4*)(xs + 2 * NN);

    const size_t qoff = ((size_t)b * MM + m) * 3;
    const float cx = new_xyz[qoff + 0];
    const float cy = new_xyz[qoff + 1];
    const float cz = new_xyz[qoff + 2];
    const float rr = kRR;

    const unsigned long long below = (1ull << lane) - 1ull;

    int my_nb = -1;
    int cnt = 0;

    // 32 chunks of 256 points; double-buffered 2-deep prefetch (static regs).
    float4 xA = X4[lane],      yA = Y4[lane],      zA = Z4[lane];       // chunk 0
    float4 xB = X4[64 + lane], yB = Y4[64 + lane], zB = Z4[64 + lane];  // chunk 1

    for (int t = 0; t < 32; t += 2) {
        {
            const float4 xx = xA, yy = yA, zz = zA;
            if (t + 2 < 32) {
                const int e = (t + 2) * 64 + lane;
                xA = X4[e]; yA = Y4[e]; zA = Z4[e];
            }
            PROCESS_CHUNK(xx, yy, zz, t * 256)
            if (cnt >= SS) break;
        }
        {
            const float4 xx = xB, yy = yB, zz = zB;
            if (t + 3 < 32) {
                const int e = (t + 3) * 64 + lane;
                xB = X4[e]; yB = Y4[e]; zB = Z4[e];
            }
            PROCESS_CHUNK(xx, yy, zz, (t + 1) * 256)
            if (cnt >= SS) break;
        }
    }

    // Padding: slots past the found count get the first found index (or 0 if none).
    int first = __shfl(my_nb, 0);
    if (first < 0) first = 0;
    if (lane < SS && my_nb < 0) my_nb = first;

    // All 64 lanes fetch slot (lane & 31)'s neighbor index.
    const int n_of = __shfl(my_nb, lane & 31);

    // Gather + write: lanes 0-31 handle channel cc, lanes 32-63 channel cc+1.
    const int s = lane & 31;
    const int chalf = lane >> 5;
    const size_t out_base = (((size_t)b * CH) * MM + m) * SS + s;
    const float* __restrict__ xb = xyz + (size_t)b * NN * 3;   // true-index AoS
    const float* __restrict__ fb = feat + (size_t)b * CC * NN;

    #pragma unroll 8
    for (int cc = 0; cc < CH + 1; cc += 2) {
        const int c = cc + chalf;
        if (c < CH) {
            float v;
            if (c < 3) {
                const float center = (c == 0) ? cx : (c == 1) ? cy : cz;
                v = __fsub_rn(xb[(size_t)n_of * 3 + c], center);
            } else {
                v = fb[(size_t)(c - 3) * NN + n_of];
            }
            out[out_base + (size_t)c * (MM * SS)] = v;
        }
    }
}

// ---------------- fallback (AoS, R2 kernel) if ws is too small --------------
__global__ __launch_bounds__(256) void qg_fused_kernel(
    const float* __restrict__ xyz, const float* __restrict__ new_xyz,
    const float* __restrict__ feat, float* __restrict__ out)
{
    const int wave = (int)((blockIdx.x * blockDim.x + threadIdx.x) >> 6);
    const int lane = (int)(threadIdx.x & 63);
    const int b = wave / MM;
    const int m = wave % MM;

    const float* __restrict__ xb = xyz + (size_t)b * NN * 3;
    const size_t qoff = ((size_t)b * MM + m) * 3;
    const float cx = new_xyz[qoff + 0];
    const float cy = new_xyz[qoff + 1];
    const float cz = new_xyz[qoff + 2];
    const float rr = kRR;

    int my_nb = -1;
    int cnt = 0;

    for (int base = 0; base < NN; base += 512) {
        float px[8], py[8], pz[8];
        #pragma unroll
        for (int k = 0; k < 8; ++k) {
            const int i = base + (k << 6) + lane;
            px[k] = xb[i * 3 + 0]; py[k] = xb[i * 3 + 1]; pz[k] = xb[i * 3 + 2];
        }
        #pragma unroll
        for (int k = 0; k < 8; ++k) {
            const float dx = __fsub_rn(px[k], cx);
            const float dy = __fsub_rn(py[k], cy);
            const float dz = __fsub_rn(pz[k], cz);
            const float d2 = __fadd_rn(__fadd_rn(__fmul_rn(dx, dx), __fmul_rn(dy, dy)),
                                       __fmul_rn(dz, dz));
            const bool hit = d2 < rr;
            const unsigned long long mask = __ballot(hit);
            const int pc = __popcll(mask);
            if (pc) {
                const int rank = cnt + (int)__popcll(mask & ((1ull << lane) - 1ull));
                const int addr = (hit && rank < 63) ? rank : 63;
                const int recv = __builtin_amdgcn_ds_permute(addr << 2,
                                                             base + (k << 6) + lane);
                if (lane >= cnt && lane < SS && (lane - cnt) < pc) my_nb = recv;
                cnt += pc;
                if (cnt >= SS) break;
            }
        }
        if (cnt >= SS) break;
    }

    int first = __shfl(my_nb, 0);
    if (first < 0) first = 0;
    if (lane < SS && my_nb < 0) my_nb = first;
    const int n_of = __shfl(my_nb, lane & 31);

    const int s = lane & 31;
    const int chalf = lane >> 5;
    const size_t out_base = (((size_t)b * CH) * MM + m) * SS + s;
    const float* __restrict__ fb = feat + (size_t)b * CC * NN;

    #pragma unroll 2
    for (int cc = 0; cc < CH + 1; cc += 2) {
        const int c = cc + chalf;
        if (c < CH) {
            float v;
            if (c < 3) {
                const float center = (c == 0) ? cx : (c == 1) ? cy : cz;
                v = __fsub_rn(xb[(size_t)n_of * 3 + c], center);
            } else {
                v = fb[(size_t)(c - 3) * NN + n_of];
            }
            out[out_base + (size_t)c * (MM * SS)] = v;
        }
    }
}

extern "C" void kernel_launch(void* const* d_in, const int* in_sizes, int n_in,
                              void* d_out, int out_size, void* d_ws, size_t ws_size,
                              hipStream_t stream) {
    const float* xyz     = (const float*)d_in[0];  // (4,8192,3)
    const float* new_xyz = (const float*)d_in[1];  // (4,4096,3)
    const float* feat    = (const float*)d_in[2];  // (4,64,8192)
    float* out = (float*)d_out;                    // (4,67,4096,32)

    const int total_waves = BB * MM;               // 16384 waves, 4 per block
    const int blocks = total_waves / 4;
    const size_t need = (size_t)BB * 3 * NN * sizeof(float);  // 384 KB SoA

    if (ws_size >= need) {
        float* xt = (float*)d_ws;
        transpose_xyz<<<(BB * NN + 255) / 256, 256, 0, stream>>>(xyz, xt);
        qg_soa_kernel<<<blocks, 256, 0, stream>>>(xt, xyz, new_xyz, feat, out);
    } else {
        qg_fused_kernel<<<blocks, 256, 0, stream>>>(xyz, new_xyz, feat, out);
    }
}

// Round 5
// 83.571 us; speedup vs baseline: 2.0752x; 2.0752x over previous
//
#include <hip/hip_runtime.h>
#include <cstdint>
#include <cstddef>

// Problem constants (fixed by setup_inputs)
#define BB 4
#define NN 8192
#define MM 4096
#define CC 64
#define SS 32
#define CH 67      // 3 (xyz) + 64 (features)

// radius^2 exactly as Python computes it: double 0.12*0.12 rounded once to f32.
__device__ __constant__ float kRR = (float)(0.12 * 0.12);

// ---- k1: xyz (B,N,3) -> permuted SoA (B,3,N) in workspace ------------------
// Point n = t*256 + J*64 + l is stored at slot t*256 + 4*l + J, so a float4
// load by lane l at chunk t yields points {t*256 + J*64 + l, J=0..3}: each
// sub-ballot J covers a CONTIGUOUS 64-index range (preserves index order).
__global__ __launch_bounds__(256) void transpose_xyz(const float* __restrict__ xyz,
                                                     float* __restrict__ xt) {
    const int p = blockIdx.x * blockDim.x + threadIdx.x;  // 0 .. B*N-1
    if (p >= BB * NN) return;
    const int b = p / NN, n = p % NN;
    const int t = n >> 8;
    const int r = n & 255;
    const int J = r >> 6;
    const int l = r & 63;
    const int slot = (t << 8) + (l << 2) + J;
    const float x = xyz[(size_t)p * 3 + 0];
    const float y = xyz[(size_t)p * 3 + 1];
    const float z = xyz[(size_t)p * 3 + 2];
    float* o = xt + (size_t)b * 3 * NN;
    o[0 * NN + slot] = x;
    o[1 * NN + slot] = y;
    o[2 * NN + slot] = z;
}

// ---- k1b: feat (B,C,N) -> feat_t (B,N,C) via LDS-tiled transpose -----------
__global__ __launch_bounds__(256) void transpose_feat(const float* __restrict__ feat,
                                                      float* __restrict__ ft) {
    __shared__ float tile[64][65];  // +1 pad: write stride-65 = 2-way (free)
    const int blk = blockIdx.x;                 // 0 .. BB*(NN/64)-1
    const int b = blk / (NN / 64);
    const int n0 = (blk % (NN / 64)) * 64;
    const int tn = (int)(threadIdx.x & 63);
    const int q = (int)(threadIdx.x >> 6);      // 0..3
    const float* fb = feat + (size_t)b * CC * NN;
    #pragma unroll
    for (int k = 0; k < 16; ++k) {
        const int c = q * 16 + k;
        tile[tn][c] = fb[(size_t)c * NN + n0 + tn];   // coalesced read along N
    }
    __syncthreads();
    float* fo = ft + ((size_t)b * NN + n0) * CC;
    #pragma unroll
    for (int k = 0; k < 16; ++k) {
        const int rn = q * 16 + k;
        fo[(size_t)rn * CC + tn] = tile[rn][tn];      // coalesced write along C
    }
}

// ---- k2: fused ball-query + group ------------------------------------------
// One wave per query. Chunk = 256 points; 4 ordered sub-ballots per chunk;
// sub-ballot J = true indices TB + J*64 + lane (contiguous, index-ordered).

#define SUB_ROUND(J, HJ)                                                       \
    {                                                                          \
        const int pc = (int)__popcll(msk##J);                                  \
        if (pc) {                                                              \
            const int rank = cnt + (int)__popcll(msk##J & below);              \
            const int addr = ((HJ) && rank < 64) ? (rank << 2) : (63 << 2);    \
            const int recv = __builtin_amdgcn_ds_permute(                      \
                addr, TB + (J << 6) + lane);                                   \
            if (lane >= cnt && lane < cnt + pc && lane < SS) my_nb = recv;     \
            cnt += pc;                                                         \
        }                                                                      \
    }

#define PROCESS_CHUNK(xx, yy, zz, TB_EXPR)                                     \
    {                                                                          \
        const int TB = (TB_EXPR);                                              \
        float dx, dy, dz, d2;                                                  \
        dx = __fsub_rn((xx).x, cx); dy = __fsub_rn((yy).x, cy);                \
        dz = __fsub_rn((zz).x, cz);                                            \
        d2 = __fadd_rn(__fadd_rn(__fmul_rn(dx, dx), __fmul_rn(dy, dy)),        \
                       __fmul_rn(dz, dz));                                     \
        const bool h0 = d2 < rr;                                               \
        dx = __fsub_rn((xx).y, cx); dy = __fsub_rn((yy).y, cy);                \
        dz = __fsub_rn((zz).y, cz);                                            \
        d2 = __fadd_rn(__fadd_rn(__fmul_rn(dx, dx), __fmul_rn(dy, dy)),        \
                       __fmul_rn(dz, dz));                                     \
        const bool h1 = d2 < rr;                                               \
        dx = __fsub_rn((xx).z, cx); dy = __fsub_rn((yy).z, cy);                \
        dz = __fsub_rn((zz).z, cz);                                            \
        d2 = __fadd_rn(__fadd_rn(__fmul_rn(dx, dx), __fmul_rn(dy, dy)),        \
                       __fmul_rn(dz, dz));                                     \
        const bool h2 = d2 < rr;                                               \
        dx = __fsub_rn((xx).w, cx); dy = __fsub_rn((yy).w, cy);                \
        dz = __fsub_rn((zz).w, cz);                                            \
        d2 = __fadd_rn(__fadd_rn(__fmul_rn(dx, dx), __fmul_rn(dy, dy)),        \
                       __fmul_rn(dz, dz));                                     \
        const bool h3 = d2 < rr;                                               \
        const unsigned long long msk0 = __ballot(h0);                          \
        const unsigned long long msk1 = __ballot(h1);                          \
        const unsigned long long msk2 = __ballot(h2);                          \
        const unsigned long long msk3 = __ballot(h3);                          \
        if (msk0 | msk1 | msk2 | msk3) {                                       \
            SUB_ROUND(0, h0)                                                   \
            SUB_ROUND(1, h1)                                                   \
            SUB_ROUND(2, h2)                                                   \
            SUB_ROUND(3, h3)                                                   \
        }                                                                      \
    }

// GATHER==1: transposed features (B,N,C); GATHER==0: original (B,C,N) path.
template <int GATHER>
__global__ __launch_bounds__(256) void qg_soa_kernel(
    const float* __restrict__ xt,       // (B,3,N) permuted SoA in ws
    const float* __restrict__ ft,       // (B,N,C) transposed feat in ws (GATHER=1)
    const float* __restrict__ xyz,      // (B,N,3) original AoS (for gather)
    const float* __restrict__ new_xyz,  // (B,M,3)
    const float* __restrict__ feat,     // (B,C,N)
    float* __restrict__ out)            // (B,67,M,32)
{
    const int wave = (int)((blockIdx.x * blockDim.x + threadIdx.x) >> 6);
    const int lane = (int)(threadIdx.x & 63);
    const int b = wave / MM;
    const int m = wave % MM;

    const float* __restrict__ xs = xt + (size_t)b * 3 * NN;
    const float4* __restrict__ X4 = (const float4*)(xs);
    const float4* __restrict__ Y4 = (const float4*)(xs + NN);
    const float4* __restrict__ Z4 = (const float4*)(xs + 2 * NN);

    const size_t qoff = ((size_t)b * MM + m) * 3;
    const float cx = new_xyz[qoff + 0];
    const float cy = new_xyz[qoff + 1];
    const float cz = new_xyz[qoff + 2];
    const float rr = kRR;

    const unsigned long long below = (1ull << lane) - 1ull;

    int my_nb = -1;
    int cnt = 0;

    // 32 chunks of 256 points; 2-deep double-buffered prefetch (static regs).
    float4 xA = X4[lane],      yA = Y4[lane],      zA = Z4[lane];
    float4 xB = X4[64 + lane], yB = Y4[64 + lane], zB = Z4[64 + lane];

    for (int t = 0; t < 32; t += 2) {
        {
            const float4 xx = xA, yy = yA, zz = zA;
            if (t + 2 < 32) {
                const int e = (t + 2) * 64 + lane;
                xA = X4[e]; yA = Y4[e]; zA = Z4[e];
            }
            PROCESS_CHUNK(xx, yy, zz, t * 256)
            if (cnt >= SS) break;
        }
        {
            const float4 xx = xB, yy = yB, zz = zB;
            if (t + 3 < 32) {
                const int e = (t + 3) * 64 + lane;
                xB = X4[e]; yB = Y4[e]; zB = Z4[e];
            }
            PROCESS_CHUNK(xx, yy, zz, (t + 1) * 256)
            if (cnt >= SS) break;
        }
    }

    // Padding: slots past the found count get the first found index (or 0).
    int first = __shfl(my_nb, 0);
    if (first < 0) first = 0;
    if (lane < SS && my_nb < 0) my_nb = first;

    const int s = lane & 31;
    const int h = lane >> 5;
    const int n_of = __shfl(my_nb, s);  // neighbor index for slot s (both halves)

    const float* __restrict__ xb = xyz + (size_t)b * NN * 3;  // true-index AoS
    const size_t obase = ((size_t)b * CH) * (size_t)(MM * SS) + (size_t)m * SS + s;

    if (GATHER) {
        // xyz channels 0..2: h==0 lanes only (32 lanes, 3 stores)
        if (h == 0) {
            const float* xr = xb + (size_t)n_of * 3;
            out[obase + 0 * (size_t)(MM * SS)] = __fsub_rn(xr[0], cx);
            out[obase + 1 * (size_t)(MM * SS)] = __fsub_rn(xr[1], cy);
            out[obase + 2 * (size_t)(MM * SS)] = __fsub_rn(xr[2], cz);
        }
        // features: lane (s,h) reads channels [h*32, h*32+32) of neighbor s:
        // 8 float4 = 128B contiguous per lane; wave touches exactly the
        // neighbor rows' lines (1x overfetch, L1-resident across j).
        const float4* fr4 = (const float4*)(ft + ((size_t)b * NN + n_of) * CC + (h << 5));
        float4 f[8];
        #pragma unroll
        for (int j = 0; j < 8; ++j) f[j] = fr4[j];
        #pragma unroll
        for (int j = 0; j < 8; ++j) {
            const size_t cb = obase + (size_t)(3 + (h << 5) + (j << 2)) * (size_t)(MM * SS);
            out[cb + 0 * (size_t)(MM * SS)] = f[j].x;
            out[cb + 1 * (size_t)(MM * SS)] = f[j].y;
            out[cb + 2 * (size_t)(MM * SS)] = f[j].z;
            out[cb + 3 * (size_t)(MM * SS)] = f[j].w;
        }
    } else {
        // Fallback gather from (B,C,N): lanes 0-31 channel cc, 32-63 cc+1.
        const float* __restrict__ fb = feat + (size_t)b * CC * NN;
        #pragma unroll 8
        for (int cc = 0; cc < CH + 1; cc += 2) {
            const int c = cc + h;
            if (c < CH) {
                float v;
                if (c < 3) {
                    const float center = (c == 0) ? cx : (c == 1) ? cy : cz;
                    v = __fsub_rn(xb[(size_t)n_of * 3 + c], center);
                } else {
                    v = fb[(size_t)(c - 3) * NN + n_of];
                }
                out[obase + (size_t)c * (size_t)(MM * SS)] = v;
            }
        }
    }
}

extern "C" void kernel_launch(void* const* d_in, const int* in_sizes, int n_in,
                              void* d_out, int out_size, void* d_ws, size_t ws_size,
                              hipStream_t stream) {
    const float* xyz     = (const float*)d_in[0];  // (4,8192,3)
    const float* new_xyz = (const float*)d_in[1];  // (4,4096,3)
    const float* feat    = (const float*)d_in[2];  // (4,64,8192)
    float* out = (float*)d_out;                    // (4,67,4096,32)

    const int total_waves = BB * MM;               // 16384 waves, 4 per block
    const int blocks = total_waves / 4;

    const size_t xt_bytes = (size_t)BB * 3 * NN * sizeof(float);        // 384 KB
    const size_t ft_bytes = (size_t)BB * NN * CC * sizeof(float);       // 8 MB
    float* xt = (float*)d_ws;
    float* ft = (float*)((char*)d_ws + xt_bytes);

    if (ws_size >= xt_bytes + ft_bytes) {
        transpose_xyz<<<(BB * NN + 255) / 256, 256, 0, stream>>>(xyz, xt);
        transpose_feat<<<BB * (NN / 64), 256, 0, stream>>>(feat, ft);
        qg_soa_kernel<1><<<blocks, 256, 0, stream>>>(xt, ft, xyz, new_xyz, feat, out);
    } else {
        transpose_xyz<<<(BB * NN + 255) / 256, 256, 0, stream>>>(xyz, xt);
        qg_soa_kernel<0><<<blocks, 256, 0, stream>>>(xt, nullptr, xyz, new_xyz, feat, out);
    }
}

// Round 6
// 80.240 us; speedup vs baseline: 2.1614x; 1.0415x over previous
//
#include <hip/hip_runtime.h>
#include <cstdint>
#include <cstddef>

// Problem constants (fixed by setup_inputs)
#define BB 4
#define NN 8192
#define MM 4096
#define CC 64
#define SS 32
#define CH 67      // 3 (xyz) + 64 (features)
#define WPB 8      // waves per block in the LDS-shared scan kernel

// radius^2 exactly as Python computes it: double 0.12*0.12 rounded once to f32.
__device__ __constant__ float kRR = (float)(0.12 * 0.12);

// ---- k1: xyz (B,N,3) -> permuted SoA (B,3,N) in workspace ------------------
// Point n = t*256 + J*64 + l is stored at slot t*256 + 4*l + J, so a float4
// load by lane l at chunk t yields points {t*256 + J*64 + l, J=0..3}: each
// sub-ballot J covers a CONTIGUOUS 64-index range (preserves index order).
__global__ __launch_bounds__(256) void transpose_xyz(const float* __restrict__ xyz,
                                                     float* __restrict__ xt) {
    const int p = blockIdx.x * blockDim.x + threadIdx.x;  // 0 .. B*N-1
    if (p >= BB * NN) return;
    const int b = p / NN, n = p % NN;
    const int t = n >> 8;
    const int r = n & 255;
    const int J = r >> 6;
    const int l = r & 63;
    const int slot = (t << 8) + (l << 2) + J;
    const float x = xyz[(size_t)p * 3 + 0];
    const float y = xyz[(size_t)p * 3 + 1];
    const float z = xyz[(size_t)p * 3 + 2];
    float* o = xt + (size_t)b * 3 * NN;
    o[0 * NN + slot] = x;
    o[1 * NN + slot] = y;
    o[2 * NN + slot] = z;
}

// ---- k1b: feat (B,C,N) -> feat_t (B,N,C) via LDS-tiled transpose -----------
__global__ __launch_bounds__(256) void transpose_feat(const float* __restrict__ feat,
                                                      float* __restrict__ ft) {
    __shared__ float tile[64][65];
    const int blk = blockIdx.x;                 // 0 .. BB*(NN/64)-1
    const int b = blk / (NN / 64);
    const int n0 = (blk % (NN / 64)) * 64;
    const int tn = (int)(threadIdx.x & 63);
    const int q = (int)(threadIdx.x >> 6);      // 0..3
    const float* fb = feat + (size_t)b * CC * NN;
    #pragma unroll
    for (int k = 0; k < 16; ++k) {
        const int c = q * 16 + k;
        tile[tn][c] = fb[(size_t)c * NN + n0 + tn];   // coalesced read along N
    }
    __syncthreads();
    float* fo = ft + ((size_t)b * NN + n0) * CC;
    #pragma unroll
    for (int k = 0; k < 16; ++k) {
        const int rn = q * 16 + k;
        fo[(size_t)rn * CC + tn] = tile[rn][tn];      // coalesced write along C
    }
}

// ---- scan macros (verified R2..R5) -----------------------------------------
#define SUB_ROUND(J, HJ)                                                       \
    {                                                                          \
        const int pc = (int)__popcll(msk##J);                                  \
        if (pc) {                                                              \
            const int rank = cnt + (int)__popcll(msk##J & below);              \
            const int addr = ((HJ) && rank < 64) ? (rank << 2) : (63 << 2);    \
            const int recv = __builtin_amdgcn_ds_permute(                      \
                addr, TB + (J << 6) + lane);                                   \
            if (lane >= cnt && lane < cnt + pc && lane < SS) my_nb = recv;     \
            cnt += pc;                                                         \
        }                                                                      \
    }

#define PROCESS_CHUNK(xx, yy, zz, TB_EXPR)                                     \
    {                                                                          \
        const int TB = (TB_EXPR);                                              \
        float dx, dy, dz, d2;                                                  \
        dx = __fsub_rn((xx).x, cx); dy = __fsub_rn((yy).x, cy);                \
        dz = __fsub_rn((zz).x, cz);                                            \
        d2 = __fadd_rn(__fadd_rn(__fmul_rn(dx, dx), __fmul_rn(dy, dy)),        \
                       __fmul_rn(dz, dz));                                     \
        const bool h0 = d2 < rr;                                               \
        dx = __fsub_rn((xx).y, cx); dy = __fsub_rn((yy).y, cy);                \
        dz = __fsub_rn((zz).y, cz);                                            \
        d2 = __fadd_rn(__fadd_rn(__fmul_rn(dx, dx), __fmul_rn(dy, dy)),        \
                       __fmul_rn(dz, dz));                                     \
        const bool h1 = d2 < rr;                                               \
        dx = __fsub_rn((xx).z, cx); dy = __fsub_rn((yy).z, cy);                \
        dz = __fsub_rn((zz).z, cz);                                            \
        d2 = __fadd_rn(__fadd_rn(__fmul_rn(dx, dx), __fmul_rn(dy, dy)),        \
                       __fmul_rn(dz, dz));                                     \
        const bool h2 = d2 < rr;                                               \
        dx = __fsub_rn((xx).w, cx); dy = __fsub_rn((yy).w, cy);                \
        dz = __fsub_rn((zz).w, cz);                                            \
        d2 = __fadd_rn(__fadd_rn(__fmul_rn(dx, dx), __fmul_rn(dy, dy)),        \
                       __fmul_rn(dz, dz));                                     \
        const bool h3 = d2 < rr;                                               \
        const unsigned long long msk0 = __ballot(h0);                          \
        const unsigned long long msk1 = __ballot(h1);                          \
        const unsigned long long msk2 = __ballot(h2);                          \
        const unsigned long long msk3 = __ballot(h3);                          \
        if (msk0 | msk1 | msk2 | msk3) {                                       \
            SUB_ROUND(0, h0)                                                   \
            SUB_ROUND(1, h1)                                                   \
            SUB_ROUND(2, h2)                                                   \
            SUB_ROUND(3, h3)                                                   \
        }                                                                      \
    }

// ---- k2: fused ball-query + group, LDS-shared chunk stream -----------------
// 512 threads = 8 waves = 8 queries per block (all same b: MM % WPB == 0).
// Waves 0-2 stage chunk t+1 (x/y/z float4[64]) into double-buffered LDS with a
// one-iteration-ahead register prefetch; all 8 waves test their own query.
__global__ __launch_bounds__(512) void qg_lds_kernel(
    const float* __restrict__ xt,       // (B,3,N) permuted SoA in ws
    const float* __restrict__ ft,       // (B,N,C) transposed feat in ws
    const float* __restrict__ xyz,      // (B,N,3) original AoS (gather)
    const float* __restrict__ new_xyz,  // (B,M,3)
    float* __restrict__ out)            // (B,67,M,32)
{
    __shared__ float4 bufX[2][64], bufY[2][64], bufZ[2][64];

    const int tid = (int)threadIdx.x;
    const int lane = tid & 63;
    const int w = tid >> 6;                       // wave 0..7
    const int wave = (int)blockIdx.x * WPB + w;
    const int b = wave >> 12;                     // / MM (block-uniform)
    const int m = wave & (MM - 1);

    const float* __restrict__ xs = xt + (size_t)b * 3 * NN;
    const float4* __restrict__ X4 = (const float4*)(xs);
    const float4* __restrict__ Y4 = (const float4*)(xs + NN);
    const float4* __restrict__ Z4 = (const float4*)(xs + 2 * NN);

    const size_t qoff = ((size_t)b * MM + m) * 3;
    const float cx = new_xyz[qoff + 0];
    const float cy = new_xyz[qoff + 1];
    const float cz = new_xyz[qoff + 2];
    const float rr = kRR;
    const unsigned long long below = (1ull << lane) - 1ull;

    int my_nb = -1;
    int cnt = 0;
    bool done = false;

    // Prologue: chunk 0 direct to LDS buf0; chunk 1 into staging regs.
    float4 vst = make_float4(0.f, 0.f, 0.f, 0.f);
    if (w == 0)      { bufX[0][lane] = X4[lane]; vst = X4[64 + lane]; }
    else if (w == 1) { bufY[0][lane] = Y4[lane]; vst = Y4[64 + lane]; }
    else if (w == 2) { bufZ[0][lane] = Z4[lane]; vst = Z4[64 + lane]; }
    __syncthreads();

    for (int t = 0; t < 32; ++t) {
        const int p = t & 1;
        if (w < 3) {
            if (t + 1 < 32) {  // write previously-loaded regs (vmcnt long satisfied)
                if (w == 0)      bufX[p ^ 1][lane] = vst;
                else if (w == 1) bufY[p ^ 1][lane] = vst;
                else             bufZ[p ^ 1][lane] = vst;
            }
            if (t + 2 < 32) {  // issue next load; hides under this iter's work
                const int e = ((t + 2) << 6) + lane;
                if (w == 0)      vst = X4[e];
                else if (w == 1) vst = Y4[e];
                else             vst = Z4[e];
            }
        }
        if (!done) {
            const float4 xx = bufX[p][lane];
            const float4 yy = bufY[p][lane];
            const float4 zz = bufZ[p][lane];
            PROCESS_CHUNK(xx, yy, zz, t << 8)
            if (cnt >= SS) done = true;
        }
        __syncthreads();
    }

    // Padding: slots past the found count get the first found index (or 0).
    int first = __shfl(my_nb, 0);
    if (first < 0) first = 0;
    if (lane < SS && my_nb < 0) my_nb = first;

    const int s = lane & 31;
    const int h = lane >> 5;
    const int n_of = __shfl(my_nb, s);  // neighbor index for slot s (both halves)

    const float* __restrict__ xb = xyz + (size_t)b * NN * 3;  // true-index AoS
    const size_t obase = ((size_t)b * CH) * (size_t)(MM * SS) + (size_t)m * SS + s;

    // xyz channels 0..2: h==0 lanes only
    if (h == 0) {
        const float* xr = xb + (size_t)n_of * 3;
        out[obase + 0 * (size_t)(MM * SS)] = __fsub_rn(xr[0], cx);
        out[obase + 1 * (size_t)(MM * SS)] = __fsub_rn(xr[1], cy);
        out[obase + 2 * (size_t)(MM * SS)] = __fsub_rn(xr[2], cz);
    }
    // features: lane (s,h) reads channels [h*32, h*32+32) of neighbor s.
    const float4* fr4 = (const float4*)(ft + ((size_t)b * NN + n_of) * CC + (h << 5));
    float4 f[8];
    #pragma unroll
    for (int j = 0; j < 8; ++j) f[j] = fr4[j];
    #pragma unroll
    for (int j = 0; j < 8; ++j) {
        const size_t cb = obase + (size_t)(3 + (h << 5) + (j << 2)) * (size_t)(MM * SS);
        out[cb + 0 * (size_t)(MM * SS)] = f[j].x;
        out[cb + 1 * (size_t)(MM * SS)] = f[j].y;
        out[cb + 2 * (size_t)(MM * SS)] = f[j].z;
        out[cb + 3 * (size_t)(MM * SS)] = f[j].w;
    }
}

// ---- fallback (R5-verified private-scan kernel, original-feat gather) ------
__global__ __launch_bounds__(256) void qg_soa_kernel(
    const float* __restrict__ xt, const float* __restrict__ xyz,
    const float* __restrict__ new_xyz, const float* __restrict__ feat,
    float* __restrict__ out)
{
    const int wave = (int)((blockIdx.x * blockDim.x + threadIdx.x) >> 6);
    const int lane = (int)(threadIdx.x & 63);
    const int b = wave / MM;
    const int m = wave % MM;

    const float* __restrict__ xs = xt + (size_t)b * 3 * NN;
    const float4* __restrict__ X4 = (const float4*)(xs);
    const float4* __restrict__ Y4 = (const float4*)(xs + NN);
    const float4* __restrict__ Z4 = (const float4*)(xs + 2 * NN);

    const size_t qoff = ((size_t)b * MM + m) * 3;
    const float cx = new_xyz[qoff + 0];
    const float cy = new_xyz[qoff + 1];
    const float cz = new_xyz[qoff + 2];
    const float rr = kRR;
    const unsigned long long below = (1ull << lane) - 1ull;

    int my_nb = -1;
    int cnt = 0;

    float4 xA = X4[lane],      yA = Y4[lane],      zA = Z4[lane];
    float4 xB = X4[64 + lane], yB = Y4[64 + lane], zB = Z4[64 + lane];

    for (int t = 0; t < 32; t += 2) {
        {
            const float4 xx = xA, yy = yA, zz = zA;
            if (t + 2 < 32) {
                const int e = (t + 2) * 64 + lane;
                xA = X4[e]; yA = Y4[e]; zA = Z4[e];
            }
            PROCESS_CHUNK(xx, yy, zz, t * 256)
            if (cnt >= SS) break;
        }
        {
            const float4 xx = xB, yy = yB, zz = zB;
            if (t + 3 < 32) {
                const int e = (t + 3) * 64 + lane;
                xB = X4[e]; yB = Y4[e]; zB = Z4[e];
            }
            PROCESS_CHUNK(xx, yy, zz, (t + 1) * 256)
            if (cnt >= SS) break;
        }
    }

    int first = __shfl(my_nb, 0);
    if (first < 0) first = 0;
    if (lane < SS && my_nb < 0) my_nb = first;

    const int s = lane & 31;
    const int h = lane >> 5;
    const int n_of = __shfl(my_nb, s);

    const float* __restrict__ xb = xyz + (size_t)b * NN * 3;
    const size_t obase = ((size_t)b * CH) * (size_t)(MM * SS) + (size_t)m * SS + s;
    const float* __restrict__ fb = feat + (size_t)b * CC * NN;
    #pragma unroll 8
    for (int cc = 0; cc < CH + 1; cc += 2) {
        const int c = cc + h;
        if (c < CH) {
            float v;
            if (c < 3) {
                const float center = (c == 0) ? cx : (c == 1) ? cy : cz;
                v = __fsub_rn(xb[(size_t)n_of * 3 + c], center);
            } else {
                v = fb[(size_t)(c - 3) * NN + n_of];
            }
            out[obase + (size_t)c * (size_t)(MM * SS)] = v;
        }
    }
}

extern "C" void kernel_launch(void* const* d_in, const int* in_sizes, int n_in,
                              void* d_out, int out_size, void* d_ws, size_t ws_size,
                              hipStream_t stream) {
    const float* xyz     = (const float*)d_in[0];  // (4,8192,3)
    const float* new_xyz = (const float*)d_in[1];  // (4,4096,3)
    const float* feat    = (const float*)d_in[2];  // (4,64,8192)
    float* out = (float*)d_out;                    // (4,67,4096,32)

    const size_t xt_bytes = (size_t)BB * 3 * NN * sizeof(float);        // 384 KB
    const size_t ft_bytes = (size_t)BB * NN * CC * sizeof(float);       // 8 MB
    float* xt = (float*)d_ws;
    float* ft = (float*)((char*)d_ws + xt_bytes);

    if (ws_size >= xt_bytes + ft_bytes) {
        transpose_xyz<<<(BB * NN + 255) / 256, 256, 0, stream>>>(xyz, xt);
        transpose_feat<<<BB * (NN / 64), 256, 0, stream>>>(feat, ft);
        qg_lds_kernel<<<(BB * MM) / WPB, 64 * WPB, 0, stream>>>(xt, ft, xyz, new_xyz, out);
    } else if (ws_size >= xt_bytes) {
        transpose_xyz<<<(BB * NN + 255) / 256, 256, 0, stream>>>(xyz, xt);
        qg_soa_kernel<<<BB * MM / 4, 256, 0, stream>>>(xt, xyz, new_xyz, feat, out);
    }
}